// Round 16
// baseline (314.467 us; speedup 1.0000x reference)
//
#include <hip/hip_runtime.h>
#include <hip/hip_bf16.h>

typedef __attribute__((ext_vector_type(4))) float f32x4;
typedef __attribute__((ext_vector_type(8))) short bf16x8;
typedef __attribute__((ext_vector_type(4))) unsigned short u16x4;
typedef unsigned int   u32;
typedef unsigned short u16;

#define DPAD 8
#define B_   8
#define C_   512
#define T_   8192
#define S_   256

// workspace byte offsets
#define OFF_WBIG 0u          // u16[1024*1024]      = 2,097,152 B
#define OFF_W2   2097152u    // u16[768*512]        =   786,432 B
#define OFF_B1   2883584u    // float[1024]
#define OFF_B2   2887680u    // float[768]
#define OFF_XT   2891776u    // u16[8*(8192+8)*512] = 67,174,400 B
#define OFF_ZT   70066176u   // u16[8*8192*512]     = 67,108,864 B

__device__ __forceinline__ u16 f2bf(float f) {
  u32 u = __builtin_bit_cast(u32, f);
  u += 0x7FFFu + ((u >> 16) & 1u);
  return (u16)(u >> 16);
}
__device__ __forceinline__ float sigm_(float x) { return 1.0f / (1.0f + __expf(-x)); }
__device__ __forceinline__ float tanh_(float x) { return 2.0f / (1.0f + __expf(-2.0f * x)) - 1.0f; }

__device__ __forceinline__ void gload_lds16(const void* g, void* l) {
  __builtin_amdgcn_global_load_lds(
      (const __attribute__((address_space(1))) void*)g,
      (__attribute__((address_space(3))) void*)l, 16, 0, 0);
}

// ---------------- pack weights / biases, zero Xt pad rows ----------------
__global__ void pack_kernel(const float* __restrict__ fw, const float* __restrict__ fb,
                            const float* __restrict__ gw, const float* __restrict__ gb,
                            const float* __restrict__ rw, const float* __restrict__ rb,
                            const float* __restrict__ sw, const float* __restrict__ sb,
                            u16* __restrict__ Wbig, u16* __restrict__ W2,
                            float* __restrict__ b1, float* __restrict__ b2,
                            u16* __restrict__ Xt)
{
  int idx = blockIdx.x * 256 + threadIdx.x;
  if (idx < 1048576) {                    // Wbig[row][k], row 2i=filter i, 2i+1=gate i
    int row = idx >> 10, k = idx & 1023;  // k<512: tap1 (x[t]); k>=512: tap0 (x[t-d])
    int i = row >> 1;
    const float* src = (row & 1) ? gw : fw;
    float v = src[((i << 9) + (k & 511)) * 2 + ((k < 512) ? 1 : 0)];
    Wbig[idx] = f2bf(v);
    return;
  }
  idx -= 1048576;
  if (idx < 393216) {                     // W2[r][k]: r<512 res, else skip
    int r = idx >> 9, k = idx & 511;
    float v = (r < 512) ? rw[(r << 9) + k] : sw[((r - 512) << 9) + k];
    W2[idx] = f2bf(v);
    return;
  }
  idx -= 393216;
  if (idx < 1024) { b1[idx] = (idx & 1) ? gb[idx >> 1] : fb[idx >> 1]; return; }
  idx -= 1024;
  if (idx < 768) { b2[idx] = (idx < 512) ? rb[idx] : sb[idx - 512]; return; }
  idx -= 768;
  if (idx < B_ * DPAD * C_) {             // zero causal pad rows of Xt
    int b = idx >> 12;                    // DPAD*C_ = 4096
    int rest = idx & 4095;
    Xt[(size_t)b * (T_ + DPAD) * C_ + rest] = 0;
  }
}

// ---------------- x [B][C][T] f32 -> Xt [B][DPAD+T][C] bf16 ----------------
__global__ __launch_bounds__(256) void transpose_kernel(const float* __restrict__ x,
                                                        u16* __restrict__ Xt)
{
  __shared__ float tile[64][65];
  int bid = blockIdx.x;
  int ct = bid & 7, tt = (bid >> 3) & 127, b = bid >> 10;
  int w = threadIdx.x >> 6, ln = threadIdx.x & 63;
  const float* xp = x + ((size_t)(b * C_ + ct * 64)) * T_ + tt * 64;
#pragma unroll
  for (int r = 0; r < 16; ++r) {
    int cl = r * 4 + w;
    tile[cl][ln] = xp[(size_t)cl * T_ + ln];
  }
  __syncthreads();
  u16* op = Xt + ((size_t)b * (T_ + DPAD) + DPAD + tt * 64) * C_ + ct * 64;
  const int q = threadIdx.x & 15;          // channel quad: c = 4q..4q+3
  const int cr = threadIdx.x >> 4;         // 0..15
#pragma unroll
  for (int r = 0; r < 4; ++r) {
    const int tl = r * 16 + cr;            // local t 0..63
    u16x4 v;
#pragma unroll
    for (int e = 0; e < 4; ++e) v[e] = f2bf(tile[q * 4 + e][tl]);
    *(u16x4*)(op + (size_t)tl * C_ + q * 4) = v;
  }
}

// ---------------- GEMM1: 256x256, BK=64, 8 waves, 1 barrier/K-tile -----------------
// Frozen at session best (round-14/15, passed 2x): round-10 k-loop skeleton +
// coalesced Zt epilogue. MfmaUtil ~32% invariant across 8 schedule variants.
__global__ __launch_bounds__(512, 2) void gemm1_kernel(
    const u16* __restrict__ W, const u16* __restrict__ Xt,
    const float* __restrict__ b1, u16* __restrict__ Zt,
    const int* __restrict__ dptr)
{
  __shared__ __align__(16) u16 smem[65536];   // 128 KB: A0 A1 B0 B1 (32 KB each)
  const int dcap = *dptr;
  const int tid = threadIdx.x;
  const int lane = tid & 63, wave = tid >> 6;
  const int wm = wave >> 2, wn = wave & 3;    // 2 x 4 waves -> 128x64 per wave
  const int lp = lane & 15, lg = lane >> 4, lx = lane & 7;

  const int bid = blockIdx.x;
  const int xcd = bid & 7;
  const int idx = bid >> 3;                 // 0..127 within XCD
  const int mt  = idx & 3;                  // m fastest -> B-panel L2 reuse
  const int nt  = (xcd << 5) | (idx >> 2);  // n-tile 0..255
  const int m0  = mt * 256;
  const int n0g = nt * 256;
  const int b = n0g >> 13, t0 = n0g & (T_ - 1);
  const size_t xtb = (size_t)b * (T_ + DPAD) * C_;

  const int srl = tid >> 3;                 // stage row-in-quarter 0..63
  const int skb = tid & 7;                  // stage 16B-block 0..7
  const int sxk = (skb ^ (srl & 7)) << 3;   // swizzled k-elem offset 0..56

  f32x4 acc[8][4];
#pragma unroll
  for (int i = 0; i < 8; ++i)
#pragma unroll
    for (int j = 0; j < 4; ++j) acc[i][j] = (f32x4){0.f, 0.f, 0.f, 0.f};

#define SQA(kt_, dd, q_) do {                                                  \
    const int row_ = (q_) * 64 + srl;                                          \
    gload_lds16(W + (size_t)(m0 + row_) * 1024 + (kt_) * 64 + sxk,             \
                smem + (dd) * 16384 + (q_) * 4096 + tid * 8);                  \
  } while (0)

#define SQB(kt_, dd, q_) do {                                                  \
    const int row_ = (q_) * 64 + srl;                                          \
    const int kg_  = (kt_) * 64 + sxk;                                         \
    const int rsh_ = (kg_ >= 512) ? dcap : 0;                                  \
    gload_lds16(Xt + xtb + (size_t)(DPAD + t0 + row_ - rsh_) * C_ + (kg_ & 511), \
                smem + 32768 + (dd) * 16384 + (q_) * 4096 + tid * 8);          \
  } while (0)

#define LDA_(Ab_, f_, kk_) \
  (*(const bf16x8*)((Ab_) + (size_t)(wm * 128 + (f_) * 16 + lp) * 64 + ((((kk_) * 4 + lg) ^ lx) << 3)))
#define LDB_(Bb_, j_, kk_) \
  (*(const bf16x8*)((Bb_) + (size_t)(wn * 64 + (j_) * 16 + lp) * 64 + ((((kk_) * 4 + lg) ^ lx) << 3)))

#define READA(a_, p_, Ab_) do {                                                \
    a_[0] = LDA_(Ab_, 2 * (p_), 0);  a_[1] = LDA_(Ab_, 2 * (p_), 1);           \
    a_[2] = LDA_(Ab_, 2 * (p_) + 1, 0); a_[3] = LDA_(Ab_, 2 * (p_) + 1, 1);    \
  } while (0)

#define MFMAPH(a_, p_) do {                                                    \
    __builtin_amdgcn_s_setprio(1);                                             \
    _Pragma("unroll") for (int kk_ = 0; kk_ < 2; ++kk_) {                      \
      _Pragma("unroll") for (int j_ = 0; j_ < 4; ++j_)                         \
        acc[2*(p_)][j_]   = __builtin_amdgcn_mfma_f32_16x16x32_bf16(a_[kk_],     bfr[j_][kk_], acc[2*(p_)][j_],   0, 0, 0); \
      _Pragma("unroll") for (int j_ = 0; j_ < 4; ++j_)                         \
        acc[2*(p_)+1][j_] = __builtin_amdgcn_mfma_f32_16x16x32_bf16(a_[2 + kk_], bfr[j_][kk_], acc[2*(p_)+1][j_], 0, 0, 0); \
    }                                                                          \
    __builtin_amdgcn_s_setprio(0);                                             \
  } while (0)

#define LGKM(n_) do { asm volatile("s_waitcnt lgkmcnt(" #n_ ")" ::: "memory"); \
                      __builtin_amdgcn_sched_barrier(0); } while (0)
#define VMW(n_)  do { asm volatile("s_waitcnt vmcnt(" #n_ ")" ::: "memory");   \
                      __builtin_amdgcn_sched_barrier(0); } while (0)

  bf16x8 bfr[4][2];
  bf16x8 aW[4], aX[4];

  // prologue: stage tile 0 into buf 0, full drain, publish
  SQB(0, 0, 0); SQB(0, 0, 1); SQB(0, 0, 2); SQB(0, 0, 3);
  SQA(0, 0, 0); SQA(0, 0, 1); SQA(0, 0, 2); SQA(0, 0, 3);
  VMW(0);
  __builtin_amdgcn_s_barrier();

  for (int t = 0; t < 15; ++t) {
    const int dd = t & 1, de = dd ^ 1;
    const u16* Ab = smem + dd * 16384;
    const u16* Bb = smem + 32768 + dd * 16384;
#pragma unroll
    for (int j = 0; j < 4; ++j) { bfr[j][0] = LDB_(Bb, j, 0); bfr[j][1] = LDB_(Bb, j, 1); }
    READA(aW, 0, Ab);
    READA(aX, 1, Ab);
    LGKM(4);                 // B + aW ready; aX in flight
    MFMAPH(aW, 0);
    SQB(t + 1, de, 0); SQB(t + 1, de, 1); SQB(t + 1, de, 2); SQB(t + 1, de, 3);
    READA(aW, 2, Ab);
    LGKM(4);                 // aX ready
    MFMAPH(aX, 1);
    SQA(t + 1, de, 0); SQA(t + 1, de, 1); SQA(t + 1, de, 2); SQA(t + 1, de, 3);
    READA(aX, 3, Ab);
    LGKM(4);                 // aW' ready
    MFMAPH(aW, 2);
    LGKM(0);                 // aX' ready
    MFMAPH(aX, 3);
    VMW(0);                  // all 8 stages of t+1 landed
    __builtin_amdgcn_s_barrier();
  }
  {  // tile 15 (buf 1), no staging
    const u16* Ab = smem + 16384;
    const u16* Bb = smem + 49152;
#pragma unroll
    for (int j = 0; j < 4; ++j) { bfr[j][0] = LDB_(Bb, j, 0); bfr[j][1] = LDB_(Bb, j, 1); }
    READA(aW, 0, Ab);
    READA(aX, 1, Ab);
    LGKM(4);
    MFMAPH(aW, 0);
    READA(aW, 2, Ab);
    LGKM(4);
    MFMAPH(aX, 1);
    READA(aX, 3, Ab);
    LGKM(4);
    MFMAPH(aW, 2);
    LGKM(0);
    MFMAPH(aX, 3);
  }

  // ---- coalesced epilogue: per-wave 64t x 72c bf16 LDS transpose ----
  __syncthreads();                          // k-loop LDS dead; repurpose smem
  u16* const wt = smem + wave * 4608;       // 64 * 72 u16 per wave (9216 B)
  const int g4 = lane >> 4, p = lane & 15;
#pragma unroll
  for (int i = 0; i < 8; ++i) {
    const int R = m0 + wm * 128 + i * 16 + (g4 << 2);
    const float bi0 = b1[R], bi1 = b1[R + 1], bi2 = b1[R + 2], bi3 = b1[R + 3];
    const int cl = i * 8 + g4 * 2;          // wave-local channel (even, 0..62)
#pragma unroll
    for (int j = 0; j < 4; ++j) {
      f32x4 v = acc[i][j];
      float z0 = tanh_(v[0] + bi0) * sigm_(v[1] + bi1);
      float z1 = tanh_(v[2] + bi2) * sigm_(v[3] + bi3);
      u32 pk = (u32)f2bf(z0) | ((u32)f2bf(z1) << 16);
      *(u32*)(wt + (j * 16 + p) * 72 + cl) = pk;
    }
  }
  // wave-private region: same-wave DS ops in order, no barrier needed
  const int cg = (m0 >> 1) + wm * 64 + (lane & 31) * 2;   // global channel (even)
  const int l5 = lane >> 5;
#pragma unroll
  for (int s = 0; s < 32; ++s) {
    const int tl = s * 2 + l5;              // local t 0..63
    u32 v = *(const u32*)(wt + tl * 72 + (lane & 31) * 2);
    *(u32*)(Zt + (size_t)(b * T_ + t0 + wn * 64 + tl) * C_ + cg) = v;
  }
#undef SQA
#undef SQB
#undef LDA_
#undef LDB_
#undef READA
#undef MFMAPH
#undef LGKM
#undef VMW
}

// ---------------- GEMM2: [768x512] x z + residual/skip epilogue ----------------
// Overlap k-loop, rule-#20-safe: 15 literal-unrolled bodies with NAMED buffer
// pointers (no runtime-indexed arrays). Per body: {ds_read frags(cur); stage
// kc+1 -> other; lgkm(0); MFMA; vmcnt(0); s_barrier} (gemm1's proven order).
// fstall overlays dead staging LDS after __syncthreads (32 KB -> 4 blocks/CU).
__global__ __launch_bounds__(256, 4) void gemm2_kernel(
    const u16* __restrict__ W2, const u16* __restrict__ Zt,
    const float* __restrict__ b2, const float* __restrict__ x,
    float* __restrict__ out)
{
  __shared__ __align__(16) u16 smem2[16384];   // 32 KB: As0|As1|Bs0|Bs1
  const int tid = threadIdx.x;
  const int lane = tid & 63, wave = tid >> 6;
  const int wm = wave >> 1, wn = wave & 1;

  const int bid = blockIdx.x;
  const int xcd = bid & 7;
  const int idx = bid >> 3;            // 0..383
  const int mt  = idx % 6;
  const int nt  = (xcd << 6) + idx / 6;
  const int m0 = mt * 128;
  const int n0g = nt * 128;
  const int b = n0g >> 13, t0 = n0g & (T_ - 1);
  const int srow = tid >> 2;
  const int skk  = (tid & 3) * 8;

  f32x4 acc[4][4];
#pragma unroll
  for (int i = 0; i < 4; ++i)
#pragma unroll
    for (int j = 0; j < 4; ++j) acc[i][j] = (f32x4){0.f, 0.f, 0.f, 0.f};

  const int aoff = (wm * 64 + (lane & 15)) * 32 + (lane >> 4) * 8;
  const int boff = (wn * 64 + (lane & 15)) * 32 + (lane >> 4) * 8;
  const size_t ztb = (size_t)b * T_ * C_;

  u16* const As0 = smem2;
  u16* const As1 = smem2 + 4096;
  u16* const Bs0 = smem2 + 8192;
  u16* const Bs1 = smem2 + 12288;

#define STAGE2(kc_, As_, Bs_) do {                                             \
    const int k_ = (kc_) * 32 + skk;                                           \
    gload_lds16(W2 + (size_t)(m0 + srow) * 512 + k_,           (As_) + tid * 8); \
    gload_lds16(W2 + (size_t)(m0 + 64 + srow) * 512 + k_,      (As_) + 2048 + tid * 8); \
    gload_lds16(Zt + ztb + (size_t)(t0 + srow) * C_ + k_,      (Bs_) + tid * 8); \
    gload_lds16(Zt + ztb + (size_t)(t0 + 64 + srow) * C_ + k_, (Bs_) + 2048 + tid * 8); \
  } while (0)

#define LGKM0 do { asm volatile("s_waitcnt lgkmcnt(0)" ::: "memory");          \
                   __builtin_amdgcn_sched_barrier(0); } while (0)
#define VMW0  do { asm volatile("s_waitcnt vmcnt(0)" ::: "memory");            \
                   __builtin_amdgcn_sched_barrier(0); } while (0)

// literal kc_; compute (Ac_,Bc_); stage kc_+1 into (An_,Bn_)
#define BODY2(kc_, Ac_, Bc_, An_, Bn_) do {                                    \
    bf16x8 af_[4], bf_[4];                                                     \
    _Pragma("unroll") for (int i_ = 0; i_ < 4; ++i_)                           \
      af_[i_] = *(const bf16x8*)((Ac_) + aoff + i_ * 512);                     \
    _Pragma("unroll") for (int j_ = 0; j_ < 4; ++j_)                           \
      bf_[j_] = *(const bf16x8*)((Bc_) + boff + j_ * 512);                     \
    STAGE2((kc_) + 1, An_, Bn_);                                               \
    LGKM0;                                                                     \
    __builtin_amdgcn_s_setprio(1);                                             \
    _Pragma("unroll") for (int i_ = 0; i_ < 4; ++i_)                           \
      _Pragma("unroll") for (int j_ = 0; j_ < 4; ++j_)                         \
        acc[i_][j_] = __builtin_amdgcn_mfma_f32_16x16x32_bf16(af_[i_], bf_[j_], acc[i_][j_], 0, 0, 0); \
    __builtin_amdgcn_s_setprio(0);                                             \
    VMW0;                                                                      \
    __builtin_amdgcn_s_barrier();                                              \
  } while (0)

  // prologue: stage kc=0 into buf0, drain, publish
  STAGE2(0, As0, Bs0);
  VMW0;
  __builtin_amdgcn_s_barrier();

  BODY2(0,  As0, Bs0, As1, Bs1);
  BODY2(1,  As1, Bs1, As0, Bs0);
  BODY2(2,  As0, Bs0, As1, Bs1);
  BODY2(3,  As1, Bs1, As0, Bs0);
  BODY2(4,  As0, Bs0, As1, Bs1);
  BODY2(5,  As1, Bs1, As0, Bs0);
  BODY2(6,  As0, Bs0, As1, Bs1);
  BODY2(7,  As1, Bs1, As0, Bs0);
  BODY2(8,  As0, Bs0, As1, Bs1);
  BODY2(9,  As1, Bs1, As0, Bs0);
  BODY2(10, As0, Bs0, As1, Bs1);
  BODY2(11, As1, Bs1, As0, Bs0);
  BODY2(12, As0, Bs0, As1, Bs1);
  BODY2(13, As1, Bs1, As0, Bs0);
  BODY2(14, As0, Bs0, As1, Bs1);
  {  // kc = 15 (buf1), no staging
    bf16x8 af_[4], bf_[4];
#pragma unroll
    for (int i_ = 0; i_ < 4; ++i_) af_[i_] = *(const bf16x8*)(As1 + aoff + i_ * 512);
#pragma unroll
    for (int j_ = 0; j_ < 4; ++j_) bf_[j_] = *(const bf16x8*)(Bs1 + boff + j_ * 512);
    LGKM0;
#pragma unroll
    for (int i_ = 0; i_ < 4; ++i_)
#pragma unroll
      for (int j_ = 0; j_ < 4; ++j_)
        acc[i_][j_] = __builtin_amdgcn_mfma_f32_16x16x32_bf16(af_[i_], bf_[j_], acc[i_][j_], 0, 0, 0);
  }

  // ---- coalesced epilogue: per-wave private LDS transpose of 16x64 quadrants ----
  __syncthreads();                              // k-loop LDS dead; overlay fstall
  float* const fst = (float*)smem2 + wave * 1088;   // 16 rows x 68 (padded)
  const int g = lane >> 4, p = lane & 15;
  const bool isres = (m0 < 512);

#pragma unroll
  for (int i = 0; i < 4; ++i) {
#pragma unroll
    for (int j = 0; j < 4; ++j)
#pragma unroll
      for (int r = 0; r < 4; ++r)
        fst[(g * 4 + r) * 68 + j * 16 + p] = acc[i][j][r];
#pragma unroll
    for (int q = 0; q < 4; ++q) {
      const int lrow = q * 4 + g;                  // 0..15
      const int row = m0 + wm * 64 + i * 16 + lrow;
      const int t = t0 + wn * 64 + p * 4;
      f32x4 v = *(const f32x4*)&fst[lrow * 68 + p * 4];
      const float bias = b2[row];
      f32x4 res;
      if (isres) {
        const size_t o = ((size_t)(b * 512 + row)) * T_ + t;
        f32x4 xv = *(const f32x4*)(x + o);
#pragma unroll
        for (int e = 0; e < 4; ++e)
          res[e] = (xv[e] + v[e] + bias) * 0.70710678118654752f;
        *(f32x4*)(out + o) = res;
      } else {
        const size_t o = (size_t)33554432 + ((size_t)(b * 256 + (row - 512))) * T_ + t;
#pragma unroll
        for (int e = 0; e < 4; ++e)
          res[e] = v[e] + bias;
        *(f32x4*)(out + o) = res;
      }
    }
  }
#undef STAGE2
#undef LGKM0
#undef VMW0
#undef BODY2
}

extern "C" void kernel_launch(void* const* d_in, const int* in_sizes, int n_in,
                              void* d_out, int out_size, void* d_ws, size_t ws_size,
                              hipStream_t stream) {
  const float* x  = (const float*)d_in[0];
  const float* fw = (const float*)d_in[1];
  const float* fb = (const float*)d_in[2];
  const float* gw = (const float*)d_in[3];
  const float* gb = (const float*)d_in[4];
  const float* rw = (const float*)d_in[5];
  const float* rb = (const float*)d_in[6];
  const float* sw = (const float*)d_in[7];
  const float* sb = (const float*)d_in[8];
  const int* dil  = (const int*)d_in[9];

  char* ws = (char*)d_ws;
  u16*   Wbig = (u16*)(ws + OFF_WBIG);
  u16*   W2   = (u16*)(ws + OFF_W2);
  float* b1   = (float*)(ws + OFF_B1);
  float* b2   = (float*)(ws + OFF_B2);
  u16*   Xt   = (u16*)(ws + OFF_XT);
  u16*   Zt   = (u16*)(ws + OFF_ZT);
  float* out  = (float*)d_out;

  hipLaunchKernelGGL(pack_kernel, dim3(5767), dim3(256), 0, stream,
                     fw, fb, gw, gb, rw, rb, sw, sb, Wbig, W2, b1, b2, Xt);
  hipLaunchKernelGGL(transpose_kernel, dim3(8192), dim3(256), 0, stream, x, Xt);
  hipLaunchKernelGGL(gemm1_kernel, dim3(1024), dim3(512), 0, stream, Wbig, Xt, b1, Zt, dil);
  hipLaunchKernelGGL(gemm2_kernel, dim3(3072), dim3(256), 0, stream, W2, Zt, b2, x, out);
}

// Round 17
// 311.564 us; speedup vs baseline: 1.0093x; 1.0093x over previous
//
#include <hip/hip_runtime.h>
#include <hip/hip_bf16.h>

typedef __attribute__((ext_vector_type(4))) float f32x4;
typedef __attribute__((ext_vector_type(8))) short bf16x8;
typedef __attribute__((ext_vector_type(4))) unsigned short u16x4;
typedef unsigned int   u32;
typedef unsigned short u16;

#define DPAD 8
#define B_   8
#define C_   512
#define T_   8192
#define S_   256

// workspace byte offsets
#define OFF_WBIG 0u          // u16[1024*1024]      = 2,097,152 B
#define OFF_W2   2097152u    // u16[768*512]        =   786,432 B
#define OFF_B1   2883584u    // float[1024]
#define OFF_B2   2887680u    // float[768]
#define OFF_XT   2891776u    // u16[8*(8192+8)*512] = 67,174,400 B
#define OFF_ZT   70066176u   // u16[8*8192*512]     = 67,108,864 B

__device__ __forceinline__ u16 f2bf(float f) {
  u32 u = __builtin_bit_cast(u32, f);
  u += 0x7FFFu + ((u >> 16) & 1u);
  return (u16)(u >> 16);
}
__device__ __forceinline__ float sigm_(float x) { return 1.0f / (1.0f + __expf(-x)); }
__device__ __forceinline__ float tanh_(float x) { return 2.0f / (1.0f + __expf(-2.0f * x)) - 1.0f; }

__device__ __forceinline__ void gload_lds16(const void* g, void* l) {
  __builtin_amdgcn_global_load_lds(
      (const __attribute__((address_space(1))) void*)g,
      (__attribute__((address_space(3))) void*)l, 16, 0, 0);
}

// ---------------- pack weights / biases, zero Xt pad rows ----------------
__global__ void pack_kernel(const float* __restrict__ fw, const float* __restrict__ fb,
                            const float* __restrict__ gw, const float* __restrict__ gb,
                            const float* __restrict__ rw, const float* __restrict__ rb,
                            const float* __restrict__ sw, const float* __restrict__ sb,
                            u16* __restrict__ Wbig, u16* __restrict__ W2,
                            float* __restrict__ b1, float* __restrict__ b2,
                            u16* __restrict__ Xt)
{
  int idx = blockIdx.x * 256 + threadIdx.x;
  if (idx < 1048576) {                    // Wbig[row][k], row 2i=filter i, 2i+1=gate i
    int row = idx >> 10, k = idx & 1023;  // k<512: tap1 (x[t]); k>=512: tap0 (x[t-d])
    int i = row >> 1;
    const float* src = (row & 1) ? gw : fw;
    float v = src[((i << 9) + (k & 511)) * 2 + ((k < 512) ? 1 : 0)];
    Wbig[idx] = f2bf(v);
    return;
  }
  idx -= 1048576;
  if (idx < 393216) {                     // W2[r][k]: r<512 res, else skip
    int r = idx >> 9, k = idx & 511;
    float v = (r < 512) ? rw[(r << 9) + k] : sw[((r - 512) << 9) + k];
    W2[idx] = f2bf(v);
    return;
  }
  idx -= 393216;
  if (idx < 1024) { b1[idx] = (idx & 1) ? gb[idx >> 1] : fb[idx >> 1]; return; }
  idx -= 1024;
  if (idx < 768) { b2[idx] = (idx < 512) ? rb[idx] : sb[idx - 512]; return; }
  idx -= 768;
  if (idx < B_ * DPAD * C_) {             // zero causal pad rows of Xt
    int b = idx >> 12;                    // DPAD*C_ = 4096
    int rest = idx & 4095;
    Xt[(size_t)b * (T_ + DPAD) * C_ + rest] = 0;
  }
}

// ---------------- x [B][C][T] f32 -> Xt [B][DPAD+T][C] bf16 ----------------
__global__ __launch_bounds__(256) void transpose_kernel(const float* __restrict__ x,
                                                        u16* __restrict__ Xt)
{
  __shared__ float tile[64][65];
  int bid = blockIdx.x;
  int ct = bid & 7, tt = (bid >> 3) & 127, b = bid >> 10;
  int w = threadIdx.x >> 6, ln = threadIdx.x & 63;
  const float* xp = x + ((size_t)(b * C_ + ct * 64)) * T_ + tt * 64;
#pragma unroll
  for (int r = 0; r < 16; ++r) {
    int cl = r * 4 + w;
    tile[cl][ln] = xp[(size_t)cl * T_ + ln];
  }
  __syncthreads();
  u16* op = Xt + ((size_t)b * (T_ + DPAD) + DPAD + tt * 64) * C_ + ct * 64;
  const int q = threadIdx.x & 15;          // channel quad: c = 4q..4q+3
  const int cr = threadIdx.x >> 4;         // 0..15
#pragma unroll
  for (int r = 0; r < 4; ++r) {
    const int tl = r * 16 + cr;            // local t 0..63
    u16x4 v;
#pragma unroll
    for (int e = 0; e < 4; ++e) v[e] = f2bf(tile[q * 4 + e][tl]);
    *(u16x4*)(op + (size_t)tl * C_ + q * 4) = v;
  }
}

// ---------------- GEMM1: 256x256, BK=64, 8 waves, 1 barrier/K-tile -----------------
// Frozen at session best: round-10 k-loop skeleton + coalesced Zt epilogue.
// MfmaUtil ~32% invariant across 8 schedule variants; structure ceiling here.
__global__ __launch_bounds__(512, 2) void gemm1_kernel(
    const u16* __restrict__ W, const u16* __restrict__ Xt,
    const float* __restrict__ b1, u16* __restrict__ Zt,
    const int* __restrict__ dptr)
{
  __shared__ __align__(16) u16 smem[65536];   // 128 KB: A0 A1 B0 B1 (32 KB each)
  const int dcap = *dptr;
  const int tid = threadIdx.x;
  const int lane = tid & 63, wave = tid >> 6;
  const int wm = wave >> 2, wn = wave & 3;    // 2 x 4 waves -> 128x64 per wave
  const int lp = lane & 15, lg = lane >> 4, lx = lane & 7;

  const int bid = blockIdx.x;
  const int xcd = bid & 7;
  const int idx = bid >> 3;                 // 0..127 within XCD
  const int mt  = idx & 3;                  // m fastest -> B-panel L2 reuse
  const int nt  = (xcd << 5) | (idx >> 2);  // n-tile 0..255
  const int m0  = mt * 256;
  const int n0g = nt * 256;
  const int b = n0g >> 13, t0 = n0g & (T_ - 1);
  const size_t xtb = (size_t)b * (T_ + DPAD) * C_;

  const int srl = tid >> 3;                 // stage row-in-quarter 0..63
  const int skb = tid & 7;                  // stage 16B-block 0..7
  const int sxk = (skb ^ (srl & 7)) << 3;   // swizzled k-elem offset 0..56

  f32x4 acc[8][4];
#pragma unroll
  for (int i = 0; i < 8; ++i)
#pragma unroll
    for (int j = 0; j < 4; ++j) acc[i][j] = (f32x4){0.f, 0.f, 0.f, 0.f};

#define SQA(kt_, dd, q_) do {                                                  \
    const int row_ = (q_) * 64 + srl;                                          \
    gload_lds16(W + (size_t)(m0 + row_) * 1024 + (kt_) * 64 + sxk,             \
                smem + (dd) * 16384 + (q_) * 4096 + tid * 8);                  \
  } while (0)

#define SQB(kt_, dd, q_) do {                                                  \
    const int row_ = (q_) * 64 + srl;                                          \
    const int kg_  = (kt_) * 64 + sxk;                                         \
    const int rsh_ = (kg_ >= 512) ? dcap : 0;                                  \
    gload_lds16(Xt + xtb + (size_t)(DPAD + t0 + row_ - rsh_) * C_ + (kg_ & 511), \
                smem + 32768 + (dd) * 16384 + (q_) * 4096 + tid * 8);          \
  } while (0)

#define LDA_(Ab_, f_, kk_) \
  (*(const bf16x8*)((Ab_) + (size_t)(wm * 128 + (f_) * 16 + lp) * 64 + ((((kk_) * 4 + lg) ^ lx) << 3)))
#define LDB_(Bb_, j_, kk_) \
  (*(const bf16x8*)((Bb_) + (size_t)(wn * 64 + (j_) * 16 + lp) * 64 + ((((kk_) * 4 + lg) ^ lx) << 3)))

#define READA(a_, p_, Ab_) do {                                                \
    a_[0] = LDA_(Ab_, 2 * (p_), 0);  a_[1] = LDA_(Ab_, 2 * (p_), 1);           \
    a_[2] = LDA_(Ab_, 2 * (p_) + 1, 0); a_[3] = LDA_(Ab_, 2 * (p_) + 1, 1);    \
  } while (0)

#define MFMAPH(a_, p_) do {                                                    \
    __builtin_amdgcn_s_setprio(1);                                             \
    _Pragma("unroll") for (int kk_ = 0; kk_ < 2; ++kk_) {                      \
      _Pragma("unroll") for (int j_ = 0; j_ < 4; ++j_)                         \
        acc[2*(p_)][j_]   = __builtin_amdgcn_mfma_f32_16x16x32_bf16(a_[kk_],     bfr[j_][kk_], acc[2*(p_)][j_],   0, 0, 0); \
      _Pragma("unroll") for (int j_ = 0; j_ < 4; ++j_)                         \
        acc[2*(p_)+1][j_] = __builtin_amdgcn_mfma_f32_16x16x32_bf16(a_[2 + kk_], bfr[j_][kk_], acc[2*(p_)+1][j_], 0, 0, 0); \
    }                                                                          \
    __builtin_amdgcn_s_setprio(0);                                             \
  } while (0)

#define LGKM(n_) do { asm volatile("s_waitcnt lgkmcnt(" #n_ ")" ::: "memory"); \
                      __builtin_amdgcn_sched_barrier(0); } while (0)
#define VMW(n_)  do { asm volatile("s_waitcnt vmcnt(" #n_ ")" ::: "memory");   \
                      __builtin_amdgcn_sched_barrier(0); } while (0)

  bf16x8 bfr[4][2];
  bf16x8 aW[4], aX[4];

  // prologue: stage tile 0 into buf 0, full drain, publish
  SQB(0, 0, 0); SQB(0, 0, 1); SQB(0, 0, 2); SQB(0, 0, 3);
  SQA(0, 0, 0); SQA(0, 0, 1); SQA(0, 0, 2); SQA(0, 0, 3);
  VMW(0);
  __builtin_amdgcn_s_barrier();

  for (int t = 0; t < 15; ++t) {
    const int dd = t & 1, de = dd ^ 1;
    const u16* Ab = smem + dd * 16384;
    const u16* Bb = smem + 32768 + dd * 16384;
#pragma unroll
    for (int j = 0; j < 4; ++j) { bfr[j][0] = LDB_(Bb, j, 0); bfr[j][1] = LDB_(Bb, j, 1); }
    READA(aW, 0, Ab);
    READA(aX, 1, Ab);
    LGKM(4);                 // B + aW ready; aX in flight
    MFMAPH(aW, 0);
    SQB(t + 1, de, 0); SQB(t + 1, de, 1); SQB(t + 1, de, 2); SQB(t + 1, de, 3);
    READA(aW, 2, Ab);
    LGKM(4);                 // aX ready
    MFMAPH(aX, 1);
    SQA(t + 1, de, 0); SQA(t + 1, de, 1); SQA(t + 1, de, 2); SQA(t + 1, de, 3);
    READA(aX, 3, Ab);
    LGKM(4);                 // aW' ready
    MFMAPH(aW, 2);
    LGKM(0);                 // aX' ready
    MFMAPH(aX, 3);
    VMW(0);                  // all 8 stages of t+1 landed
    __builtin_amdgcn_s_barrier();
  }
  {  // tile 15 (buf 1), no staging
    const u16* Ab = smem + 16384;
    const u16* Bb = smem + 49152;
#pragma unroll
    for (int j = 0; j < 4; ++j) { bfr[j][0] = LDB_(Bb, j, 0); bfr[j][1] = LDB_(Bb, j, 1); }
    READA(aW, 0, Ab);
    READA(aX, 1, Ab);
    LGKM(4);
    MFMAPH(aW, 0);
    READA(aW, 2, Ab);
    LGKM(4);
    MFMAPH(aX, 1);
    READA(aX, 3, Ab);
    LGKM(4);
    MFMAPH(aW, 2);
    LGKM(0);
    MFMAPH(aX, 3);
  }

  // ---- coalesced epilogue: per-wave 64t x 72c bf16 LDS transpose ----
  __syncthreads();                          // k-loop LDS dead; repurpose smem
  u16* const wt = smem + wave * 4608;       // 64 * 72 u16 per wave (9216 B)
  const int g4 = lane >> 4, p = lane & 15;
#pragma unroll
  for (int i = 0; i < 8; ++i) {
    const int R = m0 + wm * 128 + i * 16 + (g4 << 2);
    const float bi0 = b1[R], bi1 = b1[R + 1], bi2 = b1[R + 2], bi3 = b1[R + 3];
    const int cl = i * 8 + g4 * 2;          // wave-local channel (even, 0..62)
#pragma unroll
    for (int j = 0; j < 4; ++j) {
      f32x4 v = acc[i][j];
      float z0 = tanh_(v[0] + bi0) * sigm_(v[1] + bi1);
      float z1 = tanh_(v[2] + bi2) * sigm_(v[3] + bi3);
      u32 pk = (u32)f2bf(z0) | ((u32)f2bf(z1) << 16);
      *(u32*)(wt + (j * 16 + p) * 72 + cl) = pk;
    }
  }
  // wave-private region: same-wave DS ops in order, no barrier needed
  const int cg = (m0 >> 1) + wm * 64 + (lane & 31) * 2;   // global channel (even)
  const int l5 = lane >> 5;
#pragma unroll
  for (int s = 0; s < 32; ++s) {
    const int tl = s * 2 + l5;              // local t 0..63
    u32 v = *(const u32*)(wt + tl * 72 + (lane & 31) * 2);
    *(u32*)(Zt + (size_t)(b * T_ + t0 + wn * 64 + tl) * C_ + cg) = v;
  }
#undef SQA
#undef SQB
#undef LDA_
#undef LDB_
#undef READA
#undef MFMAPH
#undef LGKM
#undef VMW
}

// ---------------- GEMM2: [768x512] x z + residual/skip epilogue ----------------
// Drain k-loop restored (proven best at 4 blocks/CU: cross-block TLP already
// hides staging latency; overlap restructure regressed twice). Coalesced
// epilogue via disjoint wave-private fstall.
__global__ __launch_bounds__(256, 4) void gemm2_kernel(
    const u16* __restrict__ W2, const u16* __restrict__ Zt,
    const float* __restrict__ b2, const float* __restrict__ x,
    float* __restrict__ out)
{
  __shared__ __align__(16) u16 As[128 * 32];
  __shared__ __align__(16) u16 Bs[128 * 32];
  __shared__ __align__(16) float fstall[4 * 1088];   // 4 waves x 16x68 padded
  const int tid = threadIdx.x;
  const int lane = tid & 63, wave = tid >> 6;
  const int wm = wave >> 1, wn = wave & 1;

  const int bid = blockIdx.x;
  const int xcd = bid & 7;
  const int idx = bid >> 3;            // 0..383
  const int mt  = idx % 6;
  const int nt  = (xcd << 6) + idx / 6;
  const int m0 = mt * 128;
  const int n0g = nt * 128;
  const int b = n0g >> 13, t0 = n0g & (T_ - 1);
  const int srow = tid >> 2;
  const int skk  = (tid & 3) * 8;

  f32x4 acc[4][4];
#pragma unroll
  for (int i = 0; i < 4; ++i)
#pragma unroll
    for (int j = 0; j < 4; ++j) acc[i][j] = (f32x4){0.f, 0.f, 0.f, 0.f};

  const int aoff = (wm * 64 + (lane & 15)) * 32 + (lane >> 4) * 8;
  const int boff = (wn * 64 + (lane & 15)) * 32 + (lane >> 4) * 8;
  const size_t ztb = (size_t)b * T_ * C_;

  for (int kc = 0; kc < 16; ++kc) {
    const int k = kc * 32 + skk;        // 0..511
    const u16* gA = W2 + (size_t)(m0 + srow) * 512 + k;
    const u16* gB = Zt + ztb + (size_t)(t0 + srow) * C_ + k;
    gload_lds16(gA,            As + tid * 8);
    gload_lds16(gA + 64 * 512, As + 2048 + tid * 8);
    gload_lds16(gB,            Bs + tid * 8);
    gload_lds16(gB + 64 * C_,  Bs + 2048 + tid * 8);
    asm volatile("s_waitcnt vmcnt(0)" ::: "memory");
    __syncthreads();
    bf16x8 af[4], bfr[4];
#pragma unroll
    for (int i = 0; i < 4; ++i) af[i]  = *(const bf16x8*)(As + aoff + i * 512);
#pragma unroll
    for (int j = 0; j < 4; ++j) bfr[j] = *(const bf16x8*)(Bs + boff + j * 512);
#pragma unroll
    for (int i = 0; i < 4; ++i)
#pragma unroll
      for (int j = 0; j < 4; ++j)
        acc[i][j] = __builtin_amdgcn_mfma_f32_16x16x32_bf16(af[i], bfr[j], acc[i][j], 0, 0, 0);
    __syncthreads();
  }

  // ---- coalesced epilogue: per-wave private LDS transpose of 16x64 quadrants ----
  float* const fst = fstall + wave * 1088;         // 16 rows x 68 (padded)
  const int g = lane >> 4, p = lane & 15;
  const bool isres = (m0 < 512);

#pragma unroll
  for (int i = 0; i < 4; ++i) {
#pragma unroll
    for (int j = 0; j < 4; ++j)
#pragma unroll
      for (int r = 0; r < 4; ++r)
        fst[(g * 4 + r) * 68 + j * 16 + p] = acc[i][j][r];
#pragma unroll
    for (int q = 0; q < 4; ++q) {
      const int lrow = q * 4 + g;                  // 0..15
      const int row = m0 + wm * 64 + i * 16 + lrow;
      const int t = t0 + wn * 64 + p * 4;
      f32x4 v = *(const f32x4*)&fst[lrow * 68 + p * 4];
      const float bias = b2[row];
      f32x4 res;
      if (isres) {
        const size_t o = ((size_t)(b * 512 + row)) * T_ + t;
        f32x4 xv = *(const f32x4*)(x + o);
#pragma unroll
        for (int e = 0; e < 4; ++e)
          res[e] = (xv[e] + v[e] + bias) * 0.70710678118654752f;
        *(f32x4*)(out + o) = res;
      } else {
        const size_t o = (size_t)33554432 + ((size_t)(b * 256 + (row - 512))) * T_ + t;
#pragma unroll
        for (int e = 0; e < 4; ++e)
          res[e] = v[e] + bias;
        *(f32x4*)(out + o) = res;
      }
    }
  }
}

extern "C" void kernel_launch(void* const* d_in, const int* in_sizes, int n_in,
                              void* d_out, int out_size, void* d_ws, size_t ws_size,
                              hipStream_t stream) {
  const float* x  = (const float*)d_in[0];
  const float* fw = (const float*)d_in[1];
  const float* fb = (const float*)d_in[2];
  const float* gw = (const float*)d_in[3];
  const float* gb = (const float*)d_in[4];
  const float* rw = (const float*)d_in[5];
  const float* rb = (const float*)d_in[6];
  const float* sw = (const float*)d_in[7];
  const float* sb = (const float*)d_in[8];
  const int* dil  = (const int*)d_in[9];

  char* ws = (char*)d_ws;
  u16*   Wbig = (u16*)(ws + OFF_WBIG);
  u16*   W2   = (u16*)(ws + OFF_W2);
  float* b1   = (float*)(ws + OFF_B1);
  float* b2   = (float*)(ws + OFF_B2);
  u16*   Xt   = (u16*)(ws + OFF_XT);
  u16*   Zt   = (u16*)(ws + OFF_ZT);
  float* out  = (float*)d_out;

  hipLaunchKernelGGL(pack_kernel, dim3(5767), dim3(256), 0, stream,
                     fw, fb, gw, gb, rw, rb, sw, sb, Wbig, W2, b1, b2, Xt);
  hipLaunchKernelGGL(transpose_kernel, dim3(8192), dim3(256), 0, stream, x, Xt);
  hipLaunchKernelGGL(gemm1_kernel, dim3(1024), dim3(512), 0, stream, Wbig, Xt, b1, Zt, dil);
  hipLaunchKernelGGL(gemm2_kernel, dim3(3072), dim3(256), 0, stream, W2, Zt, b2, x, out);
}

// Round 18
// 311.028 us; speedup vs baseline: 1.0111x; 1.0017x over previous
//
#include <hip/hip_runtime.h>
#include <hip/hip_bf16.h>

typedef __attribute__((ext_vector_type(4))) float f32x4;
typedef __attribute__((ext_vector_type(8))) short bf16x8;
typedef __attribute__((ext_vector_type(4))) unsigned short u16x4;
typedef unsigned int   u32;
typedef unsigned short u16;

#define DPAD 8
#define B_   8
#define C_   512
#define T_   8192
#define S_   256

// workspace byte offsets
#define OFF_WBIG 0u          // u16[1024*1024]      = 2,097,152 B
#define OFF_W2   2097152u    // u16[768*512]        =   786,432 B
#define OFF_B1   2883584u    // float[1024]
#define OFF_B2   2887680u    // float[768]
#define OFF_XT   2891776u    // u16[8*(8192+8)*512] = 67,174,400 B
#define OFF_ZT   70066176u   // u16[8*8192*512]     = 67,108,864 B

__device__ __forceinline__ u16 f2bf(float f) {
  u32 u = __builtin_bit_cast(u32, f);
  u += 0x7FFFu + ((u >> 16) & 1u);
  return (u16)(u >> 16);
}
__device__ __forceinline__ float sigm_(float x) { return 1.0f / (1.0f + __expf(-x)); }
__device__ __forceinline__ float tanh_(float x) { return 2.0f / (1.0f + __expf(-2.0f * x)) - 1.0f; }

__device__ __forceinline__ void gload_lds16(const void* g, void* l) {
  __builtin_amdgcn_global_load_lds(
      (const __attribute__((address_space(1))) void*)g,
      (__attribute__((address_space(3))) void*)l, 16, 0, 0);
}

// ---------------- pack weights / biases, zero Xt pad rows ----------------
__global__ void pack_kernel(const float* __restrict__ fw, const float* __restrict__ fb,
                            const float* __restrict__ gw, const float* __restrict__ gb,
                            const float* __restrict__ rw, const float* __restrict__ rb,
                            const float* __restrict__ sw, const float* __restrict__ sb,
                            u16* __restrict__ Wbig, u16* __restrict__ W2,
                            float* __restrict__ b1, float* __restrict__ b2,
                            u16* __restrict__ Xt)
{
  int idx = blockIdx.x * 256 + threadIdx.x;
  if (idx < 1048576) {                    // Wbig[row][k], row 2i=filter i, 2i+1=gate i
    int row = idx >> 10, k = idx & 1023;  // k<512: tap1 (x[t]); k>=512: tap0 (x[t-d])
    int i = row >> 1;
    const float* src = (row & 1) ? gw : fw;
    float v = src[((i << 9) + (k & 511)) * 2 + ((k < 512) ? 1 : 0)];
    Wbig[idx] = f2bf(v);
    return;
  }
  idx -= 1048576;
  if (idx < 393216) {                     // W2[r][k]: r<512 res, else skip
    int r = idx >> 9, k = idx & 511;
    float v = (r < 512) ? rw[(r << 9) + k] : sw[((r - 512) << 9) + k];
    W2[idx] = f2bf(v);
    return;
  }
  idx -= 393216;
  if (idx < 1024) { b1[idx] = (idx & 1) ? gb[idx >> 1] : fb[idx >> 1]; return; }
  idx -= 1024;
  if (idx < 768) { b2[idx] = (idx < 512) ? rb[idx] : sb[idx - 512]; return; }
  idx -= 768;
  if (idx < B_ * DPAD * C_) {             // zero causal pad rows of Xt
    int b = idx >> 12;                    // DPAD*C_ = 4096
    int rest = idx & 4095;
    Xt[(size_t)b * (T_ + DPAD) * C_ + rest] = 0;
  }
}

// ---------------- x [B][C][T] f32 -> Xt [B][DPAD+T][C] bf16 ----------------
__global__ __launch_bounds__(256) void transpose_kernel(const float* __restrict__ x,
                                                        u16* __restrict__ Xt)
{
  __shared__ float tile[64][65];
  int bid = blockIdx.x;
  int ct = bid & 7, tt = (bid >> 3) & 127, b = bid >> 10;
  int w = threadIdx.x >> 6, ln = threadIdx.x & 63;
  const float* xp = x + ((size_t)(b * C_ + ct * 64)) * T_ + tt * 64;
#pragma unroll
  for (int r = 0; r < 16; ++r) {
    int cl = r * 4 + w;
    tile[cl][ln] = xp[(size_t)cl * T_ + ln];
  }
  __syncthreads();
  u16* op = Xt + ((size_t)b * (T_ + DPAD) + DPAD + tt * 64) * C_ + ct * 64;
  const int q = threadIdx.x & 15;          // channel quad: c = 4q..4q+3
  const int cr = threadIdx.x >> 4;         // 0..15
#pragma unroll
  for (int r = 0; r < 4; ++r) {
    const int tl = r * 16 + cr;            // local t 0..63
    u16x4 v;
#pragma unroll
    for (int e = 0; e < 4; ++e) v[e] = f2bf(tile[q * 4 + e][tl]);
    *(u16x4*)(op + (size_t)tl * C_ + q * 4) = v;
  }
}

// ---------------- GEMM1: 128x128 tile, BK=64, 4 waves, drain, 4 blocks/CU ----------
// gemm2's proven structure (drain + __syncthreads, TLP-hidden at 4 blocks/CU)
// ported to gemm1, with the proven BK=64 128B-row ^(row&7) swizzle (0 conflicts).
// High-occupancy AND conflict-free: the cell rounds 2 (conflicts) and 12
// (spill+bad swizzle) missed. All component formulas proven in prior rounds.
__global__ __launch_bounds__(256, 4) void gemm1_kernel(
    const u16* __restrict__ W, const u16* __restrict__ Xt,
    const float* __restrict__ b1, u16* __restrict__ Zt,
    const int* __restrict__ dptr)
{
  __shared__ __align__(16) u16 As[8192];      // 128 rows x 64 k (16 KB)
  __shared__ __align__(16) u16 Bs[8192];      // 128 rows x 64 k (16 KB)
  const int dcap = *dptr;
  const int tid = threadIdx.x;
  const int lane = tid & 63, wave = tid >> 6;
  const int wm = wave >> 1, wn = wave & 1;    // 2x2 waves -> 64x64 per wave
  const int lp = lane & 15, lg = lane >> 4, lx = lane & 7;

  const int bid = blockIdx.x;
  const int xcd = bid & 7;
  const int idx = bid >> 3;                 // 0..511 within XCD
  const int mt  = idx & 7;                  // m fastest -> B-panel L2 reuse
  const int nt  = (xcd << 6) | (idx >> 3);  // n-tile 0..511
  const int m0  = mt * 128;
  const int n0g = nt * 128;
  const int b = n0g >> 13, t0 = n0g & (T_ - 1);
  const size_t xtb = (size_t)b * (T_ + DPAD) * C_;

  const int srl = tid >> 3;                 // stage row-in-quarter 0..31
  const int sxk = ((tid & 7) ^ (srl & 7)) << 3;   // swizzled k-elem offset 0..56

  f32x4 acc[4][4];
#pragma unroll
  for (int i = 0; i < 4; ++i)
#pragma unroll
    for (int j = 0; j < 4; ++j) acc[i][j] = (f32x4){0.f, 0.f, 0.f, 0.f};

  // stage: quarter q covers rows q*32..q*32+31; dest = q*4096B + tid*16B (linear)
#define SQA1(kt_, q_) gload_lds16(                                             \
    W + (size_t)(m0 + (q_) * 32 + srl) * 1024 + (kt_) * 64 + sxk,              \
    As + (q_) * 2048 + tid * 8)

#define SQB1(kt_, q_) do {                                                     \
    const int rsh_ = ((kt_) >= 8) ? dcap : 0;                                  \
    const int col_ = (((kt_) & 7) << 6) + sxk;                                 \
    gload_lds16(Xt + xtb + (size_t)(DPAD + t0 + (q_) * 32 + srl - rsh_) * C_ + col_, \
                Bs + (q_) * 2048 + tid * 8);                                   \
  } while (0)

  // fragment read: row*64 + ((kk*4+lg)^lx)*8  (proven conflict-free)
#define LDA1(f_, kk_) \
  (*(const bf16x8*)(As + (size_t)(wm * 64 + (f_) * 16 + lp) * 64 + ((((kk_) * 4 + lg) ^ lx) << 3)))
#define LDB1(j_, kk_) \
  (*(const bf16x8*)(Bs + (size_t)(wn * 64 + (j_) * 16 + lp) * 64 + ((((kk_) * 4 + lg) ^ lx) << 3)))

  for (int kt = 0; kt < 16; ++kt) {
    SQA1(kt, 0); SQA1(kt, 1); SQA1(kt, 2); SQA1(kt, 3);
    SQB1(kt, 0); SQB1(kt, 1); SQB1(kt, 2); SQB1(kt, 3);
    asm volatile("s_waitcnt vmcnt(0)" ::: "memory");
    __syncthreads();
    bf16x8 af[4][2], bfr[4][2];
#pragma unroll
    for (int i = 0; i < 4; ++i) { af[i][0] = LDA1(i, 0); af[i][1] = LDA1(i, 1); }
#pragma unroll
    for (int j = 0; j < 4; ++j) { bfr[j][0] = LDB1(j, 0); bfr[j][1] = LDB1(j, 1); }
#pragma unroll
    for (int kk = 0; kk < 2; ++kk)
#pragma unroll
      for (int i = 0; i < 4; ++i)
#pragma unroll
        for (int j = 0; j < 4; ++j)
          acc[i][j] = __builtin_amdgcn_mfma_f32_16x16x32_bf16(af[i][kk], bfr[j][kk], acc[i][j], 0, 0, 0);
    __syncthreads();
  }

  // epilogue: rows R..R+3 = (filter c0, gate c0, filter c0+1, gate c0+1)
  const int g4 = lane >> 4, p = lane & 15;
#pragma unroll
  for (int i = 0; i < 4; ++i) {
    const int R = m0 + wm * 64 + i * 16 + (g4 << 2);
    const float bi0 = b1[R], bi1 = b1[R + 1], bi2 = b1[R + 2], bi3 = b1[R + 3];
    const int c0 = R >> 1;
#pragma unroll
    for (int j = 0; j < 4; ++j) {
      const int ttc = t0 + wn * 64 + j * 16 + p;
      f32x4 v = acc[i][j];
      float z0 = tanh_(v[0] + bi0) * sigm_(v[1] + bi1);
      float z1 = tanh_(v[2] + bi2) * sigm_(v[3] + bi3);
      u32 pk = (u32)f2bf(z0) | ((u32)f2bf(z1) << 16);
      *(u32*)(Zt + (size_t)(b * T_ + ttc) * C_ + c0) = pk;
    }
  }
#undef SQA1
#undef SQB1
#undef LDA1
#undef LDB1
}

// ---------------- GEMM2: [768x512] x z + residual/skip epilogue ----------------
// Drain k-loop (proven best at 4 blocks/CU) + coalesced fstall epilogue.
__global__ __launch_bounds__(256, 4) void gemm2_kernel(
    const u16* __restrict__ W2, const u16* __restrict__ Zt,
    const float* __restrict__ b2, const float* __restrict__ x,
    float* __restrict__ out)
{
  __shared__ __align__(16) u16 As[128 * 32];
  __shared__ __align__(16) u16 Bs[128 * 32];
  __shared__ __align__(16) float fstall[4 * 1088];   // 4 waves x 16x68 padded
  const int tid = threadIdx.x;
  const int lane = tid & 63, wave = tid >> 6;
  const int wm = wave >> 1, wn = wave & 1;

  const int bid = blockIdx.x;
  const int xcd = bid & 7;
  const int idx = bid >> 3;            // 0..383
  const int mt  = idx % 6;
  const int nt  = (xcd << 6) + idx / 6;
  const int m0 = mt * 128;
  const int n0g = nt * 128;
  const int b = n0g >> 13, t0 = n0g & (T_ - 1);
  const int srow = tid >> 2;
  const int skk  = (tid & 3) * 8;

  f32x4 acc[4][4];
#pragma unroll
  for (int i = 0; i < 4; ++i)
#pragma unroll
    for (int j = 0; j < 4; ++j) acc[i][j] = (f32x4){0.f, 0.f, 0.f, 0.f};

  const int aoff = (wm * 64 + (lane & 15)) * 32 + (lane >> 4) * 8;
  const int boff = (wn * 64 + (lane & 15)) * 32 + (lane >> 4) * 8;
  const size_t ztb = (size_t)b * T_ * C_;

  for (int kc = 0; kc < 16; ++kc) {
    const int k = kc * 32 + skk;        // 0..511
    const u16* gA = W2 + (size_t)(m0 + srow) * 512 + k;
    const u16* gB = Zt + ztb + (size_t)(t0 + srow) * C_ + k;
    gload_lds16(gA,            As + tid * 8);
    gload_lds16(gA + 64 * 512, As + 2048 + tid * 8);
    gload_lds16(gB,            Bs + tid * 8);
    gload_lds16(gB + 64 * C_,  Bs + 2048 + tid * 8);
    asm volatile("s_waitcnt vmcnt(0)" ::: "memory");
    __syncthreads();
    bf16x8 af[4], bfr[4];
#pragma unroll
    for (int i = 0; i < 4; ++i) af[i]  = *(const bf16x8*)(As + aoff + i * 512);
#pragma unroll
    for (int j = 0; j < 4; ++j) bfr[j] = *(const bf16x8*)(Bs + boff + j * 512);
#pragma unroll
    for (int i = 0; i < 4; ++i)
#pragma unroll
      for (int j = 0; j < 4; ++j)
        acc[i][j] = __builtin_amdgcn_mfma_f32_16x16x32_bf16(af[i], bfr[j], acc[i][j], 0, 0, 0);
    __syncthreads();
  }

  // ---- coalesced epilogue: per-wave private LDS transpose of 16x64 quadrants ----
  float* const fst = fstall + wave * 1088;         // 16 rows x 68 (padded)
  const int g = lane >> 4, p = lane & 15;
  const bool isres = (m0 < 512);

#pragma unroll
  for (int i = 0; i < 4; ++i) {
#pragma unroll
    for (int j = 0; j < 4; ++j)
#pragma unroll
      for (int r = 0; r < 4; ++r)
        fst[(g * 4 + r) * 68 + j * 16 + p] = acc[i][j][r];
#pragma unroll
    for (int q = 0; q < 4; ++q) {
      const int lrow = q * 4 + g;                  // 0..15
      const int row = m0 + wm * 64 + i * 16 + lrow;
      const int t = t0 + wn * 64 + p * 4;
      f32x4 v = *(const f32x4*)&fst[lrow * 68 + p * 4];
      const float bias = b2[row];
      f32x4 res;
      if (isres) {
        const size_t o = ((size_t)(b * 512 + row)) * T_ + t;
        f32x4 xv = *(const f32x4*)(x + o);
#pragma unroll
        for (int e = 0; e < 4; ++e)
          res[e] = (xv[e] + v[e] + bias) * 0.70710678118654752f;
        *(f32x4*)(out + o) = res;
      } else {
        const size_t o = (size_t)33554432 + ((size_t)(b * 256 + (row - 512))) * T_ + t;
#pragma unroll
        for (int e = 0; e < 4; ++e)
          res[e] = v[e] + bias;
        *(f32x4*)(out + o) = res;
      }
    }
  }
}

extern "C" void kernel_launch(void* const* d_in, const int* in_sizes, int n_in,
                              void* d_out, int out_size, void* d_ws, size_t ws_size,
                              hipStream_t stream) {
  const float* x  = (const float*)d_in[0];
  const float* fw = (const float*)d_in[1];
  const float* fb = (const float*)d_in[2];
  const float* gw = (const float*)d_in[3];
  const float* gb = (const float*)d_in[4];
  const float* rw = (const float*)d_in[5];
  const float* rb = (const float*)d_in[6];
  const float* sw = (const float*)d_in[7];
  const float* sb = (const float*)d_in[8];
  const int* dil  = (const int*)d_in[9];

  char* ws = (char*)d_ws;
  u16*   Wbig = (u16*)(ws + OFF_WBIG);
  u16*   W2   = (u16*)(ws + OFF_W2);
  float* b1   = (float*)(ws + OFF_B1);
  float* b2   = (float*)(ws + OFF_B2);
  u16*   Xt   = (u16*)(ws + OFF_XT);
  u16*   Zt   = (u16*)(ws + OFF_ZT);
  float* out  = (float*)d_out;

  hipLaunchKernelGGL(pack_kernel, dim3(5767), dim3(256), 0, stream,
                     fw, fb, gw, gb, rw, rb, sw, sb, Wbig, W2, b1, b2, Xt);
  hipLaunchKernelGGL(transpose_kernel, dim3(8192), dim3(256), 0, stream, x, Xt);
  hipLaunchKernelGGL(gemm1_kernel, dim3(4096), dim3(256), 0, stream, Wbig, Xt, b1, Zt, dil);
  hipLaunchKernelGGL(gemm2_kernel, dim3(3072), dim3(256), 0, stream, W2, Zt, b2, x, out);
}

// Round 19
// 306.177 us; speedup vs baseline: 1.0271x; 1.0158x over previous
//
#include <hip/hip_runtime.h>
#include <hip/hip_bf16.h>

typedef __attribute__((ext_vector_type(4))) float f32x4;
typedef __attribute__((ext_vector_type(8))) short bf16x8;
typedef __attribute__((ext_vector_type(4))) unsigned short u16x4;
typedef __attribute__((ext_vector_type(2))) unsigned int u32x2;
typedef unsigned int   u32;
typedef unsigned short u16;

#define DPAD 8
#define B_   8
#define C_   512
#define T_   8192
#define S_   256

// workspace byte offsets
#define OFF_WBIG 0u          // u16[1024*1024]      = 2,097,152 B
#define OFF_W2   2097152u    // u16[768*512]        =   786,432 B
#define OFF_B1   2883584u    // float[1024]
#define OFF_B2   2887680u    // float[768]
#define OFF_XT   2891776u    // u16[8*(8192+8)*512] = 67,174,400 B
#define OFF_ZT   70066176u   // u16[8*8192*512]     = 67,108,864 B

__device__ __forceinline__ u16 f2bf(float f) {
  u32 u = __builtin_bit_cast(u32, f);
  u += 0x7FFFu + ((u >> 16) & 1u);
  return (u16)(u >> 16);
}
__device__ __forceinline__ float sigm_(float x) { return 1.0f / (1.0f + __expf(-x)); }
__device__ __forceinline__ float tanh_(float x) { return 2.0f / (1.0f + __expf(-2.0f * x)) - 1.0f; }

__device__ __forceinline__ void gload_lds16(const void* g, void* l) {
  __builtin_amdgcn_global_load_lds(
      (const __attribute__((address_space(1))) void*)g,
      (__attribute__((address_space(3))) void*)l, 16, 0, 0);
}

// ---------------- pack weights / biases, zero Xt pad rows ----------------
__global__ void pack_kernel(const float* __restrict__ fw, const float* __restrict__ fb,
                            const float* __restrict__ gw, const float* __restrict__ gb,
                            const float* __restrict__ rw, const float* __restrict__ rb,
                            const float* __restrict__ sw, const float* __restrict__ sb,
                            u16* __restrict__ Wbig, u16* __restrict__ W2,
                            float* __restrict__ b1, float* __restrict__ b2,
                            u16* __restrict__ Xt)
{
  int idx = blockIdx.x * 256 + threadIdx.x;
  if (idx < 1048576) {                    // Wbig[row][k], row 2i=filter i, 2i+1=gate i
    int row = idx >> 10, k = idx & 1023;  // k<512: tap1 (x[t]); k>=512: tap0 (x[t-d])
    int i = row >> 1;
    const float* src = (row & 1) ? gw : fw;
    float v = src[((i << 9) + (k & 511)) * 2 + ((k < 512) ? 1 : 0)];
    Wbig[idx] = f2bf(v);
    return;
  }
  idx -= 1048576;
  if (idx < 393216) {                     // W2[r][k]: r<512 res, else skip
    int r = idx >> 9, k = idx & 511;
    float v = (r < 512) ? rw[(r << 9) + k] : sw[((r - 512) << 9) + k];
    W2[idx] = f2bf(v);
    return;
  }
  idx -= 393216;
  if (idx < 1024) { b1[idx] = (idx & 1) ? gb[idx >> 1] : fb[idx >> 1]; return; }
  idx -= 1024;
  if (idx < 768) { b2[idx] = (idx < 512) ? rb[idx] : sb[idx - 512]; return; }
  idx -= 768;
  if (idx < B_ * DPAD * C_) {             // zero causal pad rows of Xt
    int b = idx >> 12;                    // DPAD*C_ = 4096
    int rest = idx & 4095;
    Xt[(size_t)b * (T_ + DPAD) * C_ + rest] = 0;
  }
}

// ---------------- x [B][C][T] f32 -> Xt [B][DPAD+T][C] bf16 ----------------
__global__ __launch_bounds__(256) void transpose_kernel(const float* __restrict__ x,
                                                        u16* __restrict__ Xt)
{
  __shared__ float tile[64][65];
  int bid = blockIdx.x;
  int ct = bid & 7, tt = (bid >> 3) & 127, b = bid >> 10;
  int w = threadIdx.x >> 6, ln = threadIdx.x & 63;
  const float* xp = x + ((size_t)(b * C_ + ct * 64)) * T_ + tt * 64;
#pragma unroll
  for (int r = 0; r < 16; ++r) {
    int cl = r * 4 + w;
    tile[cl][ln] = xp[(size_t)cl * T_ + ln];
  }
  __syncthreads();
  u16* op = Xt + ((size_t)b * (T_ + DPAD) + DPAD + tt * 64) * C_ + ct * 64;
  const int q = threadIdx.x & 15;          // channel quad: c = 4q..4q+3
  const int cr = threadIdx.x >> 4;         // 0..15
#pragma unroll
  for (int r = 0; r < 4; ++r) {
    const int tl = r * 16 + cr;            // local t 0..63
    u16x4 v;
#pragma unroll
    for (int e = 0; e < 4; ++e) v[e] = f2bf(tile[q * 4 + e][tl]);
    *(u16x4*)(op + (size_t)tl * C_ + q * 4) = v;
  }
}

// ---------------- GEMM1: 128x128 tile, BK=64, 4 waves, drain, 4 blocks/CU ----------
// Round-18's winning structure (160 us, MfmaUtil 40, occ 41%, 0 conflicts) +
// the coalesced Zt epilogue re-attached (per-wave 64t x 32c LDS transpose ->
// dwordx2 stores = 8 x 64B contiguous segments per wave-instr, full-line writes).
__global__ __launch_bounds__(256, 4) void gemm1_kernel(
    const u16* __restrict__ W, const u16* __restrict__ Xt,
    const float* __restrict__ b1, u16* __restrict__ Zt,
    const int* __restrict__ dptr)
{
  __shared__ __align__(16) u16 smem[16384];   // 32 KB: As = [0,8192), Bs = [8192,16384)
  u16* const As = smem;
  u16* const Bs = smem + 8192;
  const int dcap = *dptr;
  const int tid = threadIdx.x;
  const int lane = tid & 63, wave = tid >> 6;
  const int wm = wave >> 1, wn = wave & 1;    // 2x2 waves -> 64x64 per wave
  const int lp = lane & 15, lg = lane >> 4, lx = lane & 7;

  const int bid = blockIdx.x;
  const int xcd = bid & 7;
  const int idx = bid >> 3;                 // 0..511 within XCD
  const int mt  = idx & 7;                  // m fastest -> B-panel L2 reuse
  const int nt  = (xcd << 6) | (idx >> 3);  // n-tile 0..511
  const int m0  = mt * 128;
  const int n0g = nt * 128;
  const int b = n0g >> 13, t0 = n0g & (T_ - 1);
  const size_t xtb = (size_t)b * (T_ + DPAD) * C_;

  const int srl = tid >> 3;                 // stage row-in-quarter 0..31
  const int sxk = ((tid & 7) ^ (srl & 7)) << 3;   // swizzled k-elem offset 0..56

  f32x4 acc[4][4];
#pragma unroll
  for (int i = 0; i < 4; ++i)
#pragma unroll
    for (int j = 0; j < 4; ++j) acc[i][j] = (f32x4){0.f, 0.f, 0.f, 0.f};

#define SQA1(kt_, q_) gload_lds16(                                             \
    W + (size_t)(m0 + (q_) * 32 + srl) * 1024 + (kt_) * 64 + sxk,              \
    As + (q_) * 2048 + tid * 8)

#define SQB1(kt_, q_) do {                                                     \
    const int rsh_ = ((kt_) >= 8) ? dcap : 0;                                  \
    const int col_ = (((kt_) & 7) << 6) + sxk;                                 \
    gload_lds16(Xt + xtb + (size_t)(DPAD + t0 + (q_) * 32 + srl - rsh_) * C_ + col_, \
                Bs + (q_) * 2048 + tid * 8);                                   \
  } while (0)

#define LDA1(f_, kk_) \
  (*(const bf16x8*)(As + (size_t)(wm * 64 + (f_) * 16 + lp) * 64 + ((((kk_) * 4 + lg) ^ lx) << 3)))
#define LDB1(j_, kk_) \
  (*(const bf16x8*)(Bs + (size_t)(wn * 64 + (j_) * 16 + lp) * 64 + ((((kk_) * 4 + lg) ^ lx) << 3)))

  for (int kt = 0; kt < 16; ++kt) {
    SQA1(kt, 0); SQA1(kt, 1); SQA1(kt, 2); SQA1(kt, 3);
    SQB1(kt, 0); SQB1(kt, 1); SQB1(kt, 2); SQB1(kt, 3);
    asm volatile("s_waitcnt vmcnt(0)" ::: "memory");
    __syncthreads();
    bf16x8 af[4][2], bfr[4][2];
#pragma unroll
    for (int i = 0; i < 4; ++i) { af[i][0] = LDA1(i, 0); af[i][1] = LDA1(i, 1); }
#pragma unroll
    for (int j = 0; j < 4; ++j) { bfr[j][0] = LDB1(j, 0); bfr[j][1] = LDB1(j, 1); }
#pragma unroll
    for (int kk = 0; kk < 2; ++kk)
#pragma unroll
      for (int i = 0; i < 4; ++i)
#pragma unroll
        for (int j = 0; j < 4; ++j)
          acc[i][j] = __builtin_amdgcn_mfma_f32_16x16x32_bf16(af[i][kk], bfr[j][kk], acc[i][j], 0, 0, 0);
    __syncthreads();
  }

  // ---- coalesced epilogue: per-wave 64t x 32c transpose via LDS ----
  // wave (wm,wn) owns channels cg0 = (m0>>1)+wm*32 .. +31, t = t0+wn*64 .. +63.
  __syncthreads();                          // k-loop LDS dead; repurpose
  u32* const wt32 = (u32*)smem + wave * 1152;   // 64 rows x 18 u32 (pad 2) = 4608 B
  const int g4 = lane >> 4, p = lane & 15;
#pragma unroll
  for (int i = 0; i < 4; ++i) {
    const int R = m0 + wm * 64 + i * 16 + (g4 << 2);
    const float bi0 = b1[R], bi1 = b1[R + 1], bi2 = b1[R + 2], bi3 = b1[R + 3];
#pragma unroll
    for (int j = 0; j < 4; ++j) {
      f32x4 v = acc[i][j];
      float z0 = tanh_(v[0] + bi0) * sigm_(v[1] + bi1);
      float z1 = tanh_(v[2] + bi2) * sigm_(v[3] + bi3);
      u32 pk = (u32)f2bf(z0) | ((u32)f2bf(z1) << 16);
      wt32[(j * 16 + p) * 18 + i * 4 + g4] = pk;   // row = local t, col = local ch/2
    }
  }
  // wave-private region, same-wave DS in-order: read back along channels, store
  // dwordx2 -> 8 lanes cover 64B contiguous; 8 rows per wave-instr.
  const u32 cg0h = ((u32)(m0 >> 2)) + (u32)wm * 16;   // u32-index base of channel
  u32* const ztb32 = (u32*)Zt;
#pragma unroll
  for (int s = 0; s < 8; ++s) {
    const int tl = s * 8 + (lane >> 3);    // local t 0..63
    const int cc = (lane & 7) * 2;         // u32 col 0..14
    u32x2 v = *(const u32x2*)&wt32[tl * 18 + cc];
    *(u32x2*)&ztb32[(size_t)(b * T_ + t0 + wn * 64 + tl) * 256 + cg0h + cc] = v;
  }
#undef SQA1
#undef SQB1
#undef LDA1
#undef LDB1
}

// ---------------- GEMM2: [768x512] x z + residual/skip epilogue ----------------
// Drain k-loop (proven best at 4 blocks/CU) + coalesced fstall epilogue.
__global__ __launch_bounds__(256, 4) void gemm2_kernel(
    const u16* __restrict__ W2, const u16* __restrict__ Zt,
    const float* __restrict__ b2, const float* __restrict__ x,
    float* __restrict__ out)
{
  __shared__ __align__(16) u16 As[128 * 32];
  __shared__ __align__(16) u16 Bs[128 * 32];
  __shared__ __align__(16) float fstall[4 * 1088];   // 4 waves x 16x68 padded
  const int tid = threadIdx.x;
  const int lane = tid & 63, wave = tid >> 6;
  const int wm = wave >> 1, wn = wave & 1;

  const int bid = blockIdx.x;
  const int xcd = bid & 7;
  const int idx = bid >> 3;            // 0..383
  const int mt  = idx % 6;
  const int nt  = (xcd << 6) + idx / 6;
  const int m0 = mt * 128;
  const int n0g = nt * 128;
  const int b = n0g >> 13, t0 = n0g & (T_ - 1);
  const int srow = tid >> 2;
  const int skk  = (tid & 3) * 8;

  f32x4 acc[4][4];
#pragma unroll
  for (int i = 0; i < 4; ++i)
#pragma unroll
    for (int j = 0; j < 4; ++j) acc[i][j] = (f32x4){0.f, 0.f, 0.f, 0.f};

  const int aoff = (wm * 64 + (lane & 15)) * 32 + (lane >> 4) * 8;
  const int boff = (wn * 64 + (lane & 15)) * 32 + (lane >> 4) * 8;
  const size_t ztb = (size_t)b * T_ * C_;

  for (int kc = 0; kc < 16; ++kc) {
    const int k = kc * 32 + skk;        // 0..511
    const u16* gA = W2 + (size_t)(m0 + srow) * 512 + k;
    const u16* gB = Zt + ztb + (size_t)(t0 + srow) * C_ + k;
    gload_lds16(gA,            As + tid * 8);
    gload_lds16(gA + 64 * 512, As + 2048 + tid * 8);
    gload_lds16(gB,            Bs + tid * 8);
    gload_lds16(gB + 64 * C_,  Bs + 2048 + tid * 8);
    asm volatile("s_waitcnt vmcnt(0)" ::: "memory");
    __syncthreads();
    bf16x8 af[4], bfr[4];
#pragma unroll
    for (int i = 0; i < 4; ++i) af[i]  = *(const bf16x8*)(As + aoff + i * 512);
#pragma unroll
    for (int j = 0; j < 4; ++j) bfr[j] = *(const bf16x8*)(Bs + boff + j * 512);
#pragma unroll
    for (int i = 0; i < 4; ++i)
#pragma unroll
      for (int j = 0; j < 4; ++j)
        acc[i][j] = __builtin_amdgcn_mfma_f32_16x16x32_bf16(af[i], bfr[j], acc[i][j], 0, 0, 0);
    __syncthreads();
  }

  // ---- coalesced epilogue: per-wave private LDS transpose of 16x64 quadrants ----
  float* const fst = fstall + wave * 1088;         // 16 rows x 68 (padded)
  const int g = lane >> 4, p = lane & 15;
  const bool isres = (m0 < 512);

#pragma unroll
  for (int i = 0; i < 4; ++i) {
#pragma unroll
    for (int j = 0; j < 4; ++j)
#pragma unroll
      for (int r = 0; r < 4; ++r)
        fst[(g * 4 + r) * 68 + j * 16 + p] = acc[i][j][r];
#pragma unroll
    for (int q = 0; q < 4; ++q) {
      const int lrow = q * 4 + g;                  // 0..15
      const int row = m0 + wm * 64 + i * 16 + lrow;
      const int t = t0 + wn * 64 + p * 4;
      f32x4 v = *(const f32x4*)&fst[lrow * 68 + p * 4];
      const float bias = b2[row];
      f32x4 res;
      if (isres) {
        const size_t o = ((size_t)(b * 512 + row)) * T_ + t;
        f32x4 xv = *(const f32x4*)(x + o);
#pragma unroll
        for (int e = 0; e < 4; ++e)
          res[e] = (xv[e] + v[e] + bias) * 0.70710678118654752f;
        *(f32x4*)(out + o) = res;
      } else {
        const size_t o = (size_t)33554432 + ((size_t)(b * 256 + (row - 512))) * T_ + t;
#pragma unroll
        for (int e = 0; e < 4; ++e)
          res[e] = v[e] + bias;
        *(f32x4*)(out + o) = res;
      }
    }
  }
}

extern "C" void kernel_launch(void* const* d_in, const int* in_sizes, int n_in,
                              void* d_out, int out_size, void* d_ws, size_t ws_size,
                              hipStream_t stream) {
  const float* x  = (const float*)d_in[0];
  const float* fw = (const float*)d_in[1];
  const float* fb = (const float*)d_in[2];
  const float* gw = (const float*)d_in[3];
  const float* gb = (const float*)d_in[4];
  const float* rw = (const float*)d_in[5];
  const float* rb = (const float*)d_in[6];
  const float* sw = (const float*)d_in[7];
  const float* sb = (const float*)d_in[8];
  const int* dil  = (const int*)d_in[9];

  char* ws = (char*)d_ws;
  u16*   Wbig = (u16*)(ws + OFF_WBIG);
  u16*   W2   = (u16*)(ws + OFF_W2);
  float* b1   = (float*)(ws + OFF_B1);
  float* b2   = (float*)(ws + OFF_B2);
  u16*   Xt   = (u16*)(ws + OFF_XT);
  u16*   Zt   = (u16*)(ws + OFF_ZT);
  float* out  = (float*)d_out;

  hipLaunchKernelGGL(pack_kernel, dim3(5767), dim3(256), 0, stream,
                     fw, fb, gw, gb, rw, rb, sw, sb, Wbig, W2, b1, b2, Xt);
  hipLaunchKernelGGL(transpose_kernel, dim3(8192), dim3(256), 0, stream, x, Xt);
  hipLaunchKernelGGL(gemm1_kernel, dim3(4096), dim3(256), 0, stream, Wbig, Xt, b1, Zt, dil);
  hipLaunchKernelGGL(gemm2_kernel, dim3(3072), dim3(256), 0, stream, W2, Zt, b2, x, out);
}